// Round 1
// baseline (278.639 us; speedup 1.0000x reference)
//
#include <hip/hip_runtime.h>
#include <hip/hip_bf16.h>

// GraphAE: pseudo == 0 => only W[0] of the 8 spline matrices matters.
// Linearization: mean(h[src])@W2_0 == mean(h[src]@W2_0) -> project before gather.
// Round 10:
//  - agg kernels fused INTO the GEMM kernels: each 64-row GEMM block first
//    mean-aggregates its own 64 nodes into an LDS tile, then runs stage1/stage2.
//    Removes 2 launches, the z buffer, and the agg half of ab1 (38 MB traffic).
//  - gathers widened to 16B/lane (uint4 = 8 bf16), 8 lanes/edge x 8 slots:
//    half the load instructions per edge; reduce = shfl_xor 8/16/32.
//
// Verified MFMA layouts (guide §3): A[m=lane&15][k=(lane>>4)*8+j],
// B[k=(lane>>4)*8+j][n=lane&15], D[row=(lane>>4)*4+r][col=lane&15].

#define THREADS 256

typedef __attribute__((ext_vector_type(8))) short bf16x8;   // 8 bf16 = 4 VGPRs
typedef __attribute__((ext_vector_type(4))) float f32x4;    // acc

__device__ __forceinline__ float bf2f(unsigned short u) {
    unsigned v = ((unsigned)u) << 16;
    return __builtin_bit_cast(float, v);
}
__device__ __forceinline__ unsigned short f2bf(float f) {
    __hip_bfloat16 h = __float2bfloat16(f);   // RNE
    return __builtin_bit_cast(unsigned short, h);
}
__device__ __forceinline__ void acc8(float* f, uint4 v) {
    f[0] += bf2f((unsigned short)v.x); f[1] += bf2f((unsigned short)(v.x >> 16));
    f[2] += bf2f((unsigned short)v.y); f[3] += bf2f((unsigned short)(v.y >> 16));
    f[4] += bf2f((unsigned short)v.z); f[5] += bf2f((unsigned short)(v.z >> 16));
    f[6] += bf2f((unsigned short)v.w); f[7] += bf2f((unsigned short)(v.w >> 16));
}

// ---------------- weight pack ----------------
// Pack fp32 W (eff. K x NOUT) into MFMA B-frag layout bf16:
// dst[(((s*NB + j)*64 + lane)*8 + i] = W[s*32 + (lane>>4)*8 + i][j*16 + (lane&15)]
__device__ __forceinline__ void pack_one(unsigned short* dst,
                                         const float* W0, const float* W1,
                                         int NB, int ksplit, int colsplit,
                                         int ld0, int ld1, int t) {
    int i = t & 7, lane = (t >> 3) & 63, rest = t >> 9;
    int j = rest % NB, s = rest / NB;
    int k = s * 32 + ((lane >> 4) << 3) + i;
    int c = (j << 4) + (lane & 15);
    float v;
    if (c >= colsplit)    v = W1[(size_t)k * ld1 + (c - colsplit)];
    else if (k >= ksplit) v = W1[(size_t)(k - ksplit) * ld1 + c];
    else                  v = W0[(size_t)k * ld0 + c];
    dst[t] = f2bf(v);
}

#define BIG (1 << 30)

// prep: weight packs + x->bf16 (vectorized) + bucket histogram (edge blocks)
__global__ void prep_kernel(const float* __restrict__ W1g, const float* __restrict__ root1,
                            const float* __restrict__ W2g, const float* __restrict__ root2,
                            const float* __restrict__ dw1, const float* __restrict__ dw2,
                            const float* __restrict__ x, const int* __restrict__ dstv,
                            int* __restrict__ bcnt,
                            unsigned short* __restrict__ Pb1,   // 128x256
                            unsigned short* __restrict__ Pb2,   // 256x128
                            unsigned short* __restrict__ Pd1,   // 64x256
                            unsigned short* __restrict__ Pd2,   // 256x64
                            unsigned short* __restrict__ ab1,   // N x 128, x -> cols 64:128
                            int n, int E, int pb_pack) {
    if ((int)blockIdx.x >= pb_pack) {
        __shared__ int hist[256];
        int t = threadIdx.x;
        hist[t] = 0;
        __syncthreads();
        int e0 = ((int)blockIdx.x - pb_pack) * 4096;
#pragma unroll
        for (int i = 0; i < 16; ++i) {
            int e = e0 + t + i * 256;
            if (e < E) atomicAdd(&hist[dstv[e] >> 8], 1);
        }
        __syncthreads();
        int h = hist[t];
        if (h) atomicAdd(&bcnt[t], h);
        return;
    }
    int t = blockIdx.x * blockDim.x + threadIdx.x;
    if (t < 32768) {
        pack_one(Pb1, W1g, root1, 16, 64, BIG, 256, 256, t);
    } else if (t < 65536) {
        pack_one(Pb2, W2g, root2, 8, BIG, 64, 64, 64, t - 32768);
    } else if (t < 81920) {
        pack_one(Pd1, dw1, dw1, 16, BIG, BIG, 256, 256, t - 65536);
    } else if (t < 98304) {
        pack_one(Pd2, dw2, dw2, 4, BIG, BIG, 64, 64, t - 81920);
    } else if (t < 98304 + n * 16) {
        int u = t - 98304;
        int row = u >> 4, c4 = (u & 15) * 4;
        float4 v = *(const float4*)(x + (size_t)row * 64 + c4);
        unsigned lo = (unsigned)f2bf(v.x) | ((unsigned)f2bf(v.y) << 16);
        unsigned hi = (unsigned)f2bf(v.z) | ((unsigned)f2bf(v.w) << 16);
        uint2 o; o.x = lo; o.y = hi;
        *(uint2*)(ab1 + (size_t)row * 128 + 64 + c4) = o;
    }
}

// Pass A: partition edges into buckets of 256 consecutive dst nodes.
// Computes bucket bases via local LDS scan of bcnt; bcur are 0-based cursors.
__global__ __launch_bounds__(256) void partition_edges(
    const int* __restrict__ src, const int* __restrict__ dst,
    const int* __restrict__ bcnt, int* __restrict__ bcur,
    int* __restrict__ epack, int E) {
    __shared__ int hist[256];
    __shared__ int base[256];
    __shared__ int lcur[256];
    __shared__ int bb[256];
    int t = threadIdx.x;
    hist[t] = 0;
    __syncthreads();
    int e0 = blockIdx.x * 4096;
    int myd[16], mys[16];
#pragma unroll
    for (int i = 0; i < 16; ++i) {
        int e = e0 + t + i * 256;
        int d = (e < E) ? dst[e] : -1;
        mys[i] = (e < E) ? src[e] : 0;
        myd[i] = d;
        if (d >= 0) atomicAdd(&hist[d >> 8], 1);
    }
    // local exclusive scan of bcnt -> bucket bases
    int cb = bcnt[t];
    bb[t] = cb;
    __syncthreads();
    for (int off = 1; off < 256; off <<= 1) {
        int xv = (t >= off) ? bb[t - off] : 0;
        __syncthreads();
        bb[t] += xv;
        __syncthreads();
    }
    int bbase_t = bb[t] - cb;
    int h = hist[t];
    if (h > 0) base[t] = bbase_t + atomicAdd(&bcur[t], h);
    lcur[t] = 0;
    __syncthreads();
#pragma unroll
    for (int i = 0; i < 16; ++i) {
        int d = myd[i];
        if (d >= 0) {
            int b = d >> 8;
            int p = atomicAdd(&lcur[b], 1);
            epack[base[b] + p] = ((d & 255) << 20) | mys[i];
        }
    }
}

// Pass B: one block per bucket. Local per-node histogram + scan in LDS
// (emits offs and invd), then bucket-local ordering + coalesced esrc write.
__global__ __launch_bounds__(256) void bucket_fill2(
    const int* __restrict__ epack, const int* __restrict__ bcnt,
    int* __restrict__ offs, float* __restrict__ invd,
    int* __restrict__ esrc, int N) {
    __shared__ int sb_[256];
    __shared__ int nh[256];
    __shared__ int loff[256];
    __shared__ int ncur[256];
    __shared__ int stage[8192];
    int b = blockIdx.x, t = threadIdx.x;
    int n0 = b << 8;
    int cntn = min(256, N - n0);
    // bucket base via local scan of bcnt
    int cb = bcnt[t];
    sb_[t] = cb;
    __syncthreads();
    for (int off = 1; off < 256; off <<= 1) {
        int xv = (t >= off) ? sb_[t - off] : 0;
        __syncthreads();
        sb_[t] += xv;
        __syncthreads();
    }
    int ebase = b ? sb_[b - 1] : 0;
    int ecount = sb_[b] - ebase;
    if (b == 0 && t == 0) offs[N] = sb_[255];
    nh[t] = 0;
    __syncthreads();
    for (int i = t; i < ecount; i += 256)
        atomicAdd(&nh[epack[ebase + i] >> 20], 1);
    __syncthreads();
    int v = nh[t];
    loff[t] = v;
    __syncthreads();
    for (int off = 1; off < 256; off <<= 1) {
        int xv = (t >= off) ? loff[t - off] : 0;
        __syncthreads();
        loff[t] += xv;
        __syncthreads();
    }
    int ex = loff[t] - v;
    loff[t] = ex;
    if (t < cntn) {
        offs[n0 + t] = ebase + ex;
        invd[n0 + t] = 1.0f / (float)max(v, 1);
    }
    ncur[t] = 0;
    __syncthreads();
    bool useLds = (ecount <= 8192);
    for (int i = t; i < ecount; i += 256) {
        int p = epack[ebase + i];
        int dl = p >> 20;
        int pos = atomicAdd(&ncur[dl], 1);
        int g = loff[dl] + pos;         // bucket-local slot
        int sv = p & 0xFFFFF;
        if (useLds) stage[g] = sv;
        else        esrc[ebase + g] = sv;
    }
    __syncthreads();
    if (useLds)
        for (int i = t; i < ecount; i += 256) esrc[ebase + i] = stage[i];
}

// ---- shared agg-into-LDS helper: mean over in-neighbors of one node ----
// 8 lanes/edge (16B = 8 bf16), 8 edge slots per wave. Returns r[0..7] summed
// across slots (valid in all lanes; slot==0 lanes hold cols c*8..c*8+7).
__device__ __forceinline__ void gather_node(const unsigned short* __restrict__ tb,
                                            const int* __restrict__ esrc,
                                            int s0, int e0, int slot, float* r) {
    float a0[8] = {}, a1[8] = {};
    int j = s0;
    for (; j + 16 <= e0; j += 16) {
        int i0 = esrc[j + slot], i1 = esrc[j + 8 + slot];
        uint4 v0 = *(const uint4*)(tb + (size_t)i0 * 128);
        uint4 v1 = *(const uint4*)(tb + (size_t)i1 * 128);
        acc8(a0, v0); acc8(a1, v1);
    }
    if (j + 8 <= e0) {
        int i0 = esrc[j + slot];
        uint4 v0 = *(const uint4*)(tb + (size_t)i0 * 128);
        acc8(a0, v0);
        j += 8;
    }
    if (slot < e0 - j) {
        int i0 = esrc[j + slot];
        uint4 v0 = *(const uint4*)(tb + (size_t)i0 * 128);
        acc8(a1, v0);
    }
#pragma unroll
    for (int k = 0; k < 8; ++k) {
        r[k] = a0[k] + a1[k];
        r[k] += __shfl_xor(r[k], 8);
        r[k] += __shfl_xor(r[k], 16);
        r[k] += __shfl_xor(r[k], 32);
    }
}

// ---------------- fused layer-1: agg1 + L1 GEMM + L2 projection ----------------
// Phase 0: at[64][72] = mean(x_bf16[src]) for this block's 64 nodes (LDS).
// Stage 1: T = relu([at | x] @ Wp1 + b1)   (K=128, T: 64x256 in LDS)
// Stage 2: hwroot = T @ [W2_0 | root2]     (bf16, N x 128)
__global__ __launch_bounds__(256) void gemm1_fused(
    const unsigned short* __restrict__ ab1,    // N x 128, cols 64:128 = x bf16
    const int* __restrict__ esrc, const int* __restrict__ offs,
    const float* __restrict__ invd,
    const unsigned short* __restrict__ Bp1, const float* __restrict__ bias1,
    const unsigned short* __restrict__ Bp2,
    unsigned short* __restrict__ hwroot, int n)
{
    __shared__ unsigned short at[64][72];     // stride 144B: 16B-aligned, 2-way banks (free)
    __shared__ unsigned short ht[64][264];
    const int m0 = blockIdx.x * 64;
    const int lane = threadIdx.x & 63;
    const int w = threadIdx.x >> 6;
    const int quad = lane >> 4;
    const int l16 = lane & 15;

    // ---- phase 0: aggregate this block's 64 nodes ----
    {
        const int slot = lane >> 3, c = lane & 7;
        const unsigned short* tb = ab1 + 64 + c * 8;   // gather x cols (64:128)
        for (int pass = 0; pass < 16; ++pass) {
            int node = m0 + (pass << 2) + w;
            if (node >= n) continue;                   // wave-uniform
            int s0 = offs[node], e0 = offs[node + 1];
            float r[8];
            gather_node(tb, esrc, s0, e0, slot, r);
            if (slot == 0) {
                float iv = invd[node];
                unsigned p0 = (unsigned)f2bf(r[0] * iv) | ((unsigned)f2bf(r[1] * iv) << 16);
                unsigned p1 = (unsigned)f2bf(r[2] * iv) | ((unsigned)f2bf(r[3] * iv) << 16);
                unsigned p2 = (unsigned)f2bf(r[4] * iv) | ((unsigned)f2bf(r[5] * iv) << 16);
                unsigned p3 = (unsigned)f2bf(r[6] * iv) | ((unsigned)f2bf(r[7] * iv) << 16);
                uint4 o; o.x = p0; o.y = p1; o.z = p2; o.w = p3;
                *(uint4*)&at[(pass << 2) + w][c * 8] = o;
            }
        }
    }
    __syncthreads();

    // ---- stage 1: K=128, A = [at (LDS) | x (global)] ----
    {
        f32x4 acc[4][4] = {};
        const unsigned short* xrow = ab1 + (size_t)(m0 + l16) * 128 + 64 + quad * 8;
#pragma unroll
        for (int s = 0; s < 4; ++s) {
            bf16x8 a[4];
#pragma unroll
            for (int mb = 0; mb < 4; ++mb) {
                if (s < 2)
                    a[mb] = *(const bf16x8*)&at[mb * 16 + l16][s * 32 + quad * 8];
                else
                    a[mb] = *(const bf16x8*)(xrow + (size_t)mb * 16 * 128 + (s - 2) * 32);
            }
#pragma unroll
            for (int jn = 0; jn < 4; ++jn) {
                int j = w * 4 + jn;
                bf16x8 b = *(const bf16x8*)(Bp1 + ((size_t)(s * 16 + j) * 64 + lane) * 8);
#pragma unroll
                for (int mb = 0; mb < 4; ++mb)
                    acc[mb][jn] = __builtin_amdgcn_mfma_f32_16x16x32_bf16(a[mb], b, acc[mb][jn], 0, 0, 0);
            }
        }
#pragma unroll
        for (int jn = 0; jn < 4; ++jn) {
            int col = (w * 4 + jn) * 16 + l16;
            float bv = bias1[col];
#pragma unroll
            for (int mb = 0; mb < 4; ++mb)
#pragma unroll
                for (int r = 0; r < 4; ++r) {
                    int row = mb * 16 + quad * 4 + r;
                    ht[row][col] = f2bf(fmaxf(acc[mb][jn][r] + bv, 0.f));
                }
        }
    }
    __syncthreads();

    // ---- stage 2: K=256, N2=128, bf16 out ----
    {
        f32x4 acc[4][2] = {};
        for (int s = 0; s < 8; ++s) {
            bf16x8 a[4];
#pragma unroll
            for (int mb = 0; mb < 4; ++mb)
                a[mb] = *(const bf16x8*)&ht[mb * 16 + l16][s * 32 + quad * 8];
#pragma unroll
            for (int jn = 0; jn < 2; ++jn) {
                int j = w * 2 + jn;
                bf16x8 b = *(const bf16x8*)(Bp2 + ((size_t)(s * 8 + j) * 64 + lane) * 8);
#pragma unroll
                for (int mb = 0; mb < 4; ++mb)
                    acc[mb][jn] = __builtin_amdgcn_mfma_f32_16x16x32_bf16(a[mb], b, acc[mb][jn], 0, 0, 0);
            }
        }
#pragma unroll
        for (int jn = 0; jn < 2; ++jn) {
            int col = (w * 2 + jn) * 16 + l16;
#pragma unroll
            for (int mb = 0; mb < 4; ++mb)
#pragma unroll
                for (int r = 0; r < 4; ++r) {
                    int row = m0 + mb * 16 + quad * 4 + r;
                    if (row < n)
                        hwroot[(size_t)row * 128 + col] = f2bf(acc[mb][jn][r]);
                }
        }
    }
}

// ---------------- fused layer-2 + decoder: agg2 + dec1 + dec2 ----------------
// Phase 0: zt[64][72] = mean(hw[src]) + hroot + b2 (LDS), hwroot = [hw | hroot].
// Stage 1: T = relu(zt @ dec_w1 + db1)     (K=64)
// Stage 2: out = T @ dec_w2 + db2          (fp32, N x 64)
__global__ __launch_bounds__(256) void gemm2_fused(
    const unsigned short* __restrict__ hwroot, // N x 128 bf16
    const int* __restrict__ esrc, const int* __restrict__ offs,
    const float* __restrict__ invd, const float* __restrict__ b2,
    const unsigned short* __restrict__ Pd1, const float* __restrict__ db1,
    const unsigned short* __restrict__ Pd2, const float* __restrict__ db2,
    float* __restrict__ out, int n)
{
    __shared__ unsigned short zt[64][72];
    __shared__ unsigned short ht[64][264];
    const int m0 = blockIdx.x * 64;
    const int lane = threadIdx.x & 63;
    const int w = threadIdx.x >> 6;
    const int quad = lane >> 4;
    const int l16 = lane & 15;

    // ---- phase 0: z = mean(hw[src]) + hroot + b2 ----
    {
        const int slot = lane >> 3, c = lane & 7;
        const unsigned short* tb = hwroot + c * 8;     // gather hw cols (0:64)
        for (int pass = 0; pass < 16; ++pass) {
            int node = m0 + (pass << 2) + w;
            if (node >= n) continue;
            int s0 = offs[node], e0 = offs[node + 1];
            float r[8];
            gather_node(tb, esrc, s0, e0, slot, r);
            if (slot == 0) {
                float iv = invd[node];
                uint4 hr = *(const uint4*)(hwroot + (size_t)node * 128 + 64 + c * 8);
                float4 bA = *(const float4*)(b2 + c * 8);
                float4 bB = *(const float4*)(b2 + c * 8 + 4);
                float v0 = r[0] * iv + bf2f((unsigned short)hr.x) + bA.x;
                float v1 = r[1] * iv + bf2f((unsigned short)(hr.x >> 16)) + bA.y;
                float v2 = r[2] * iv + bf2f((unsigned short)hr.y) + bA.z;
                float v3 = r[3] * iv + bf2f((unsigned short)(hr.y >> 16)) + bA.w;
                float v4 = r[4] * iv + bf2f((unsigned short)hr.z) + bB.x;
                float v5 = r[5] * iv + bf2f((unsigned short)(hr.z >> 16)) + bB.y;
                float v6 = r[6] * iv + bf2f((unsigned short)hr.w) + bB.z;
                float v7 = r[7] * iv + bf2f((unsigned short)(hr.w >> 16)) + bB.w;
                unsigned p0 = (unsigned)f2bf(v0) | ((unsigned)f2bf(v1) << 16);
                unsigned p1 = (unsigned)f2bf(v2) | ((unsigned)f2bf(v3) << 16);
                unsigned p2 = (unsigned)f2bf(v4) | ((unsigned)f2bf(v5) << 16);
                unsigned p3 = (unsigned)f2bf(v6) | ((unsigned)f2bf(v7) << 16);
                uint4 o; o.x = p0; o.y = p1; o.z = p2; o.w = p3;
                *(uint4*)&zt[(pass << 2) + w][c * 8] = o;
            }
        }
    }
    __syncthreads();

    // ---- stage 1: K=64 from zt ----
    {
        f32x4 acc[4][4] = {};
#pragma unroll
        for (int s = 0; s < 2; ++s) {
            bf16x8 a[4];
#pragma unroll
            for (int mb = 0; mb < 4; ++mb)
                a[mb] = *(const bf16x8*)&zt[mb * 16 + l16][s * 32 + quad * 8];
#pragma unroll
            for (int jn = 0; jn < 4; ++jn) {
                int j = w * 4 + jn;
                bf16x8 b = *(const bf16x8*)(Pd1 + ((size_t)(s * 16 + j) * 64 + lane) * 8);
#pragma unroll
                for (int mb = 0; mb < 4; ++mb)
                    acc[mb][jn] = __builtin_amdgcn_mfma_f32_16x16x32_bf16(a[mb], b, acc[mb][jn], 0, 0, 0);
            }
        }
#pragma unroll
        for (int jn = 0; jn < 4; ++jn) {
            int col = (w * 4 + jn) * 16 + l16;
            float bv = db1[col];
#pragma unroll
            for (int mb = 0; mb < 4; ++mb)
#pragma unroll
                for (int r = 0; r < 4; ++r) {
                    int row = mb * 16 + quad * 4 + r;
                    ht[row][col] = f2bf(fmaxf(acc[mb][jn][r] + bv, 0.f));
                }
        }
    }
    __syncthreads();

    // ---- stage 2: K=256, N2=64, fp32 out ----
    {
        f32x4 acc[4] = {};
        for (int s = 0; s < 8; ++s) {
            bf16x8 a[4];
#pragma unroll
            for (int mb = 0; mb < 4; ++mb)
                a[mb] = *(const bf16x8*)&ht[mb * 16 + l16][s * 32 + quad * 8];
            bf16x8 b = *(const bf16x8*)(Pd2 + ((size_t)(s * 4 + w) * 64 + lane) * 8);
#pragma unroll
            for (int mb = 0; mb < 4; ++mb)
                acc[mb] = __builtin_amdgcn_mfma_f32_16x16x32_bf16(a[mb], b, acc[mb], 0, 0, 0);
        }
        int col = w * 16 + l16;
        float bv = db2[col];
#pragma unroll
        for (int mb = 0; mb < 4; ++mb)
#pragma unroll
            for (int r = 0; r < 4; ++r) {
                int row = m0 + mb * 16 + quad * 4 + r;
                if (row < n)
                    out[(size_t)row * 64 + col] = acc[mb][r] + bv;
            }
    }
}

extern "C" void kernel_launch(void* const* d_in, const int* in_sizes, int n_in,
                              void* d_out, int out_size, void* d_ws, size_t ws_size,
                              hipStream_t stream) {
    const float* x      = (const float*)d_in[0];
    const int*   ei     = (const int*)d_in[1];
    const float* W1g    = (const float*)d_in[2];   // (8,64,256): [0] = first 16384
    const float* root1  = (const float*)d_in[3];
    const float* b1     = (const float*)d_in[4];
    const float* W2g    = (const float*)d_in[5];   // (8,256,64): [0] = first 16384
    const float* root2  = (const float*)d_in[6];
    const float* b2     = (const float*)d_in[7];
    const float* dw1    = (const float*)d_in[8];
    const float* db1    = (const float*)d_in[9];
    const float* dw2    = (const float*)d_in[10];
    const float* db2    = (const float*)d_in[11];
    float* out = (float*)d_out;

    const int N = in_sizes[0] / 64;
    const int E = in_sizes[1] / 2;
    const int Npad = N + 64;
    const int* srcv = ei;
    const int* dstv = ei + E;

    char* ws = (char*)d_ws;
    auto alloc = [&](size_t bytes) -> void* {
        void* p = (void*)ws;
        ws += (bytes + 255) & ~(size_t)255;
        return p;
    };
    int*   bcnt   = (int*)alloc(1024);               // per-bucket counts (256)
    int*   bcur   = (int*)alloc(1024);               // 0-based bucket cursors
    int*   offs   = (int*)alloc((size_t)(N + 1) * 4);
    float* invd   = (float*)alloc((size_t)N * 4);
    int*   esrc   = (int*)alloc((size_t)E * 4);
    int*   epack  = (int*)alloc((size_t)E * 4);
    unsigned short* Pb1 = (unsigned short*)alloc(32768 * 2);
    unsigned short* Pb2 = (unsigned short*)alloc(32768 * 2);
    unsigned short* Pd1 = (unsigned short*)alloc(16384 * 2);
    unsigned short* Pd2 = (unsigned short*)alloc(16384 * 2);
    unsigned short* ab1    = (unsigned short*)alloc((size_t)Npad * 128 * 2);  // [unused | xb]
    unsigned short* hwroot = (unsigned short*)alloc((size_t)Npad * 128 * 2);

    hipMemsetAsync(bcnt, 0, 2048, stream);           // bcnt + bcur (adjacent)

    int gb = (N + 63) / 64;
    int nbkt = (N + 255) / 256;
    int pa = (E + 4095) / 4096;
    int pb_pack = (98304 + N * 16 + THREADS - 1) / THREADS;

    // packs + x->bf16 + bucket histogram (one kernel, disjoint block ranges)
    prep_kernel<<<pb_pack + pa, THREADS, 0, stream>>>(
        W1g, root1, W2g, root2, dw1, dw2, x, dstv, bcnt,
        Pb1, Pb2, Pd1, Pd2, ab1, N, E, pb_pack);
    // bucket-level CSR (bases computed locally from bcnt in each kernel)
    partition_edges<<<pa, 256, 0, stream>>>(srcv, dstv, bcnt, bcur, epack, E);
    bucket_fill2<<<nbkt, 256, 0, stream>>>(epack, bcnt, offs, invd, esrc, N);

    // fused [agg1 -> L1 GEMM -> L2 projection]
    gemm1_fused<<<gb, 256, 0, stream>>>(ab1, esrc, offs, invd, Pb1, b1, Pb2, hwroot, N);
    // fused [agg2(+root+bias) -> dec1 -> dec2]
    gemm2_fused<<<gb, 256, 0, stream>>>(hwroot, esrc, offs, invd, b2,
                                        Pd1, db1, Pd2, db2, out, N);
}

// Round 2
// 264.377 us; speedup vs baseline: 1.0539x; 1.0539x over previous
//
#include <hip/hip_runtime.h>
#include <hip/hip_bf16.h>

// GraphAE: pseudo == 0 => only W[0] of the 8 spline matrices matters.
// Linearization: mean(h[src])@W2_0 == mean(h[src]@W2_0) -> project before gather.
// Round 11:
//  - Fusion of agg into GEMM reverted (R10: latency-bound, 3.1k waves).
//  - CSR build replaced: 2-pass bucket sort (2x 196-block kernels, ~100us)
//    -> counting sort: deg[] via global atomics in prep, offs/cur via tiny
//    scan kernel, edge-parallel scatter (782 blocks). epack deleted.
//  - gathers widened to 16B/lane (uint4 = 8 bf16), 8 lanes/edge x 8 slots:
//    half the load instructions per edge; reduce = shfl_xor 8/16/32.
//
// Verified MFMA layouts (guide §3): A[m=lane&15][k=(lane>>4)*8+j],
// B[k=(lane>>4)*8+j][n=lane&15], D[row=(lane>>4)*4+r][col=lane&15].

#define THREADS 256

typedef __attribute__((ext_vector_type(8))) short bf16x8;   // 8 bf16 = 4 VGPRs
typedef __attribute__((ext_vector_type(4))) float f32x4;    // acc

__device__ __forceinline__ float bf2f(unsigned short u) {
    unsigned v = ((unsigned)u) << 16;
    return __builtin_bit_cast(float, v);
}
__device__ __forceinline__ unsigned short f2bf(float f) {
    __hip_bfloat16 h = __float2bfloat16(f);   // RNE
    return __builtin_bit_cast(unsigned short, h);
}
__device__ __forceinline__ void acc8(float* f, uint4 v) {
    f[0] += bf2f((unsigned short)v.x); f[1] += bf2f((unsigned short)(v.x >> 16));
    f[2] += bf2f((unsigned short)v.y); f[3] += bf2f((unsigned short)(v.y >> 16));
    f[4] += bf2f((unsigned short)v.z); f[5] += bf2f((unsigned short)(v.z >> 16));
    f[6] += bf2f((unsigned short)v.w); f[7] += bf2f((unsigned short)(v.w >> 16));
}

// ---------------- weight pack ----------------
// Pack fp32 W (eff. K x NOUT) into MFMA B-frag layout bf16:
// dst[(((s*NB + j)*64 + lane)*8 + i] = W[s*32 + (lane>>4)*8 + i][j*16 + (lane&15)]
__device__ __forceinline__ void pack_one(unsigned short* dst,
                                         const float* W0, const float* W1,
                                         int NB, int ksplit, int colsplit,
                                         int ld0, int ld1, int t) {
    int i = t & 7, lane = (t >> 3) & 63, rest = t >> 9;
    int j = rest % NB, s = rest / NB;
    int k = s * 32 + ((lane >> 4) << 3) + i;
    int c = (j << 4) + (lane & 15);
    float v;
    if (c >= colsplit)    v = W1[(size_t)k * ld1 + (c - colsplit)];
    else if (k >= ksplit) v = W1[(size_t)(k - ksplit) * ld1 + c];
    else                  v = W0[(size_t)k * ld0 + c];
    dst[t] = f2bf(v);
}

#define BIG (1 << 30)

// prep: weight packs + x->bf16 (vectorized) + deg count + bucket histogram
__global__ void prep_kernel(const float* __restrict__ W1g, const float* __restrict__ root1,
                            const float* __restrict__ W2g, const float* __restrict__ root2,
                            const float* __restrict__ dw1, const float* __restrict__ dw2,
                            const float* __restrict__ x, const int* __restrict__ dstv,
                            int* __restrict__ bcnt, int* __restrict__ deg,
                            unsigned short* __restrict__ Pb1,   // 128x256
                            unsigned short* __restrict__ Pb2,   // 256x128
                            unsigned short* __restrict__ Pd1,   // 64x256
                            unsigned short* __restrict__ Pd2,   // 256x64
                            unsigned short* __restrict__ ab1,   // N x 128, x -> cols 64:128
                            int n, int E, int pb_pack) {
    if ((int)blockIdx.x >= pb_pack) {
        __shared__ int hist[256];
        int t = threadIdx.x;
        hist[t] = 0;
        __syncthreads();
        int e0 = ((int)blockIdx.x - pb_pack) * 4096;
#pragma unroll
        for (int i = 0; i < 16; ++i) {
            int e = e0 + t + i * 256;
            if (e < E) {
                int d = dstv[e];
                atomicAdd(&hist[d >> 8], 1);
                atomicAdd(&deg[d], 1);
            }
        }
        __syncthreads();
        int h = hist[t];
        if (h) atomicAdd(&bcnt[t], h);
        return;
    }
    int t = blockIdx.x * blockDim.x + threadIdx.x;
    if (t < 32768) {
        pack_one(Pb1, W1g, root1, 16, 64, BIG, 256, 256, t);
    } else if (t < 65536) {
        pack_one(Pb2, W2g, root2, 8, BIG, 64, 64, 64, t - 32768);
    } else if (t < 81920) {
        pack_one(Pd1, dw1, dw1, 16, BIG, BIG, 256, 256, t - 65536);
    } else if (t < 98304) {
        pack_one(Pd2, dw2, dw2, 4, BIG, BIG, 64, 64, t - 81920);
    } else if (t < 98304 + n * 16) {
        int u = t - 98304;
        int row = u >> 4, c4 = (u & 15) * 4;
        float4 v = *(const float4*)(x + (size_t)row * 64 + c4);
        unsigned lo = (unsigned)f2bf(v.x) | ((unsigned)f2bf(v.y) << 16);
        unsigned hi = (unsigned)f2bf(v.z) | ((unsigned)f2bf(v.w) << 16);
        uint2 o; o.x = lo; o.y = hi;
        *(uint2*)(ab1 + (size_t)row * 128 + 64 + c4) = o;
    }
}

// offs/cur/invd from deg: per-bucket base via redundant LDS scan of bcnt,
// per-node exclusive scan of deg within the bucket. One block per bucket.
__global__ __launch_bounds__(256) void build_offs(
    const int* __restrict__ bcnt, const int* __restrict__ deg,
    int* __restrict__ offs, int* __restrict__ cur, float* __restrict__ invd,
    int N, int E) {
    __shared__ int sb_[256];
    __shared__ int ld[256];
    int b = blockIdx.x, t = threadIdx.x;
    int n0 = b << 8;
    sb_[t] = bcnt[t];
    __syncthreads();
    for (int off = 1; off < 256; off <<= 1) {
        int xv = (t >= off) ? sb_[t - off] : 0;
        __syncthreads();
        sb_[t] += xv;
        __syncthreads();
    }
    int ebase = b ? sb_[b - 1] : 0;
    int node = n0 + t;
    int d = (node < N) ? deg[node] : 0;
    ld[t] = d;
    __syncthreads();
    for (int off = 1; off < 256; off <<= 1) {
        int xv = (t >= off) ? ld[t - off] : 0;
        __syncthreads();
        ld[t] += xv;
        __syncthreads();
    }
    int ex = ld[t] - d;
    if (node < N) {
        offs[node] = ebase + ex;
        cur[node]  = ebase + ex;
        invd[node] = 1.0f / (float)max(d, 1);
    }
    if (b == 0 && t == 0) offs[N] = E;
}

// edge-parallel counting-sort scatter: esrc grouped by dst via atomic cursors
__global__ __launch_bounds__(256) void scatter_edges(
    const int* __restrict__ src, const int* __restrict__ dst,
    int* __restrict__ cur, int* __restrict__ esrc, int E) {
    int e0 = blockIdx.x * 1024 + threadIdx.x;
#pragma unroll
    for (int i = 0; i < 4; ++i) {
        int e = e0 + i * 256;
        if (e < E) {
            int d = dst[e];
            int p = atomicAdd(&cur[d], 1);
            esrc[p] = src[e];
        }
    }
}

// ---------------- gathers: 16B/lane, 8 edges per wave-instr, 16-edge unroll ----
// lane = slot(8) x c(8); lane loads features [c*8, c*8+8) of edge (j+slot).
// agg1 = mean(x[src]): reads ab1 cols 64:128, writes ab1 cols 0:64.
__global__ void agg_x4(unsigned short* __restrict__ ab1, const int* __restrict__ esrc,
                       const int* __restrict__ offs, const float* __restrict__ invd,
                       int n) {
    int node = blockIdx.x * 4 + (threadIdx.x >> 6);
    if (node >= n) return;
    int l = threadIdx.x & 63;
    int slot = l >> 3, c = l & 7;
    const unsigned short* xb = ab1 + 64 + c * 8;
    int s = offs[node], e = offs[node + 1];
    float a0[8] = {}, a1[8] = {};
    int j = s;
    for (; j + 16 <= e; j += 16) {
        int i0 = esrc[j + slot], i1 = esrc[j + 8 + slot];
        uint4 v0 = *(const uint4*)(xb + (size_t)i0 * 128);
        uint4 v1 = *(const uint4*)(xb + (size_t)i1 * 128);
        acc8(a0, v0); acc8(a1, v1);
    }
    if (j + 8 <= e) {
        int i0 = esrc[j + slot];
        uint4 v0 = *(const uint4*)(xb + (size_t)i0 * 128);
        acc8(a0, v0);
        j += 8;
    }
    if (slot < e - j) {
        int i0 = esrc[j + slot];
        uint4 v0 = *(const uint4*)(xb + (size_t)i0 * 128);
        acc8(a1, v0);
    }
    float r[8];
#pragma unroll
    for (int k = 0; k < 8; ++k) {
        r[k] = a0[k] + a1[k];
        r[k] += __shfl_xor(r[k], 8);
        r[k] += __shfl_xor(r[k], 16);
        r[k] += __shfl_xor(r[k], 32);
    }
    if (slot == 0) {
        float iv = invd[node];
        unsigned p0 = (unsigned)f2bf(r[0] * iv) | ((unsigned)f2bf(r[1] * iv) << 16);
        unsigned p1 = (unsigned)f2bf(r[2] * iv) | ((unsigned)f2bf(r[3] * iv) << 16);
        unsigned p2 = (unsigned)f2bf(r[4] * iv) | ((unsigned)f2bf(r[5] * iv) << 16);
        unsigned p3 = (unsigned)f2bf(r[6] * iv) | ((unsigned)f2bf(r[7] * iv) << 16);
        uint4 o; o.x = p0; o.y = p1; o.z = p2; o.w = p3;
        *(uint4*)(ab1 + (size_t)node * 128 + c * 8) = o;
    }
}

// z = mean(hw[src]) + hroot + b2 ; hwroot N x 128 bf16 (0:64 hw, 64:128 hroot)
__global__ void agg_z4(const unsigned short* __restrict__ hwroot,
                       const int* __restrict__ esrc, const int* __restrict__ offs,
                       const float* __restrict__ invd, const float* __restrict__ b2,
                       unsigned short* __restrict__ z, int n) {
    int node = blockIdx.x * 4 + (threadIdx.x >> 6);
    if (node >= n) return;
    int l = threadIdx.x & 63;
    int slot = l >> 3, c = l & 7;
    const unsigned short* hb = hwroot + c * 8;
    int s = offs[node], e = offs[node + 1];
    float a0[8] = {}, a1[8] = {};
    int j = s;
    for (; j + 16 <= e; j += 16) {
        int i0 = esrc[j + slot], i1 = esrc[j + 8 + slot];
        uint4 v0 = *(const uint4*)(hb + (size_t)i0 * 128);
        uint4 v1 = *(const uint4*)(hb + (size_t)i1 * 128);
        acc8(a0, v0); acc8(a1, v1);
    }
    if (j + 8 <= e) {
        int i0 = esrc[j + slot];
        uint4 v0 = *(const uint4*)(hb + (size_t)i0 * 128);
        acc8(a0, v0);
        j += 8;
    }
    if (slot < e - j) {
        int i0 = esrc[j + slot];
        uint4 v0 = *(const uint4*)(hb + (size_t)i0 * 128);
        acc8(a1, v0);
    }
    float r[8];
#pragma unroll
    for (int k = 0; k < 8; ++k) {
        r[k] = a0[k] + a1[k];
        r[k] += __shfl_xor(r[k], 8);
        r[k] += __shfl_xor(r[k], 16);
        r[k] += __shfl_xor(r[k], 32);
    }
    if (slot == 0) {
        float iv = invd[node];
        uint4 hr = *(const uint4*)(hwroot + (size_t)node * 128 + 64 + c * 8);
        float4 bA = *(const float4*)(b2 + c * 8);
        float4 bB = *(const float4*)(b2 + c * 8 + 4);
        float v0 = r[0] * iv + bf2f((unsigned short)hr.x) + bA.x;
        float v1 = r[1] * iv + bf2f((unsigned short)(hr.x >> 16)) + bA.y;
        float v2 = r[2] * iv + bf2f((unsigned short)hr.y) + bA.z;
        float v3 = r[3] * iv + bf2f((unsigned short)(hr.y >> 16)) + bA.w;
        float v4 = r[4] * iv + bf2f((unsigned short)hr.z) + bB.x;
        float v5 = r[5] * iv + bf2f((unsigned short)(hr.z >> 16)) + bB.y;
        float v6 = r[6] * iv + bf2f((unsigned short)hr.w) + bB.z;
        float v7 = r[7] * iv + bf2f((unsigned short)(hr.w >> 16)) + bB.w;
        unsigned p0 = (unsigned)f2bf(v0) | ((unsigned)f2bf(v1) << 16);
        unsigned p1 = (unsigned)f2bf(v2) | ((unsigned)f2bf(v3) << 16);
        unsigned p2 = (unsigned)f2bf(v4) | ((unsigned)f2bf(v5) << 16);
        unsigned p3 = (unsigned)f2bf(v6) | ((unsigned)f2bf(v7) << 16);
        uint4 o; o.x = p0; o.y = p1; o.z = p2; o.w = p3;
        *(uint4*)(z + (size_t)node * 64 + c * 8) = o;
    }
}

// ---------------- fused double-GEMM ----------------
// Stage 1: T = relu(A @ Wp1 + bias1)  (A: n x K1 bf16, T: 64 x 256 tile in LDS)
// Stage 2: C = T @ Wp2 (+ bias2)      (C: n x (NBW2*64))
template <int K1, int NBW2, bool OUTBF>
__global__ __launch_bounds__(256) void gemm_fused(
    const unsigned short* __restrict__ A,
    const unsigned short* __restrict__ Bp1, const float* __restrict__ bias1,
    const unsigned short* __restrict__ Bp2, const float* __restrict__ bias2,
    void* __restrict__ Cv, int n)
{
    constexpr int KS1 = K1 / 32;
    constexpr int N2 = NBW2 * 64;
    constexpr int NB2 = NBW2 * 4;
    __shared__ unsigned short ht[64][264];

    const int m0 = blockIdx.x * 64;
    const int lane = threadIdx.x & 63;
    const int w = threadIdx.x >> 6;
    const int quad = lane >> 4;
    const int l16 = lane & 15;

    // ---- stage 1 ----
    {
        f32x4 acc[4][4] = {};
        const unsigned short* Arow = A + (size_t)(m0 + l16) * K1 + quad * 8;
        for (int s = 0; s < KS1; ++s) {
            bf16x8 a[4];
#pragma unroll
            for (int mb = 0; mb < 4; ++mb)
                a[mb] = *(const bf16x8*)(Arow + (size_t)mb * 16 * K1 + s * 32);
#pragma unroll
            for (int jn = 0; jn < 4; ++jn) {
                int j = w * 4 + jn;
                bf16x8 b = *(const bf16x8*)(Bp1 + ((size_t)(s * 16 + j) * 64 + lane) * 8);
#pragma unroll
                for (int mb = 0; mb < 4; ++mb)
                    acc[mb][jn] = __builtin_amdgcn_mfma_f32_16x16x32_bf16(a[mb], b, acc[mb][jn], 0, 0, 0);
            }
        }
#pragma unroll
        for (int jn = 0; jn < 4; ++jn) {
            int col = (w * 4 + jn) * 16 + l16;
            float bv = bias1[col];
#pragma unroll
            for (int mb = 0; mb < 4; ++mb)
#pragma unroll
                for (int r = 0; r < 4; ++r) {
                    int row = mb * 16 + quad * 4 + r;
                    ht[row][col] = f2bf(fmaxf(acc[mb][jn][r] + bv, 0.f));
                }
        }
    }
    __syncthreads();

    // ---- stage 2 ----
    {
        f32x4 acc[4][NBW2] = {};
        for (int s = 0; s < 8; ++s) {
            bf16x8 a[4];
#pragma unroll
            for (int mb = 0; mb < 4; ++mb)
                a[mb] = *(const bf16x8*)&ht[mb * 16 + l16][s * 32 + quad * 8];
#pragma unroll
            for (int jn = 0; jn < NBW2; ++jn) {
                int j = w * NBW2 + jn;
                bf16x8 b = *(const bf16x8*)(Bp2 + ((size_t)(s * NB2 + j) * 64 + lane) * 8);
#pragma unroll
                for (int mb = 0; mb < 4; ++mb)
                    acc[mb][jn] = __builtin_amdgcn_mfma_f32_16x16x32_bf16(a[mb], b, acc[mb][jn], 0, 0, 0);
            }
        }
#pragma unroll
        for (int jn = 0; jn < NBW2; ++jn) {
            int col = (w * NBW2 + jn) * 16 + l16;
            float bv = bias2 ? bias2[col] : 0.f;
#pragma unroll
            for (int mb = 0; mb < 4; ++mb)
#pragma unroll
                for (int r = 0; r < 4; ++r) {
                    int row = m0 + mb * 16 + quad * 4 + r;
                    if (row < n) {
                        float v = acc[mb][jn][r] + bv;
                        if (OUTBF)
                            ((unsigned short*)Cv)[(size_t)row * N2 + col] = f2bf(v);
                        else
                            ((float*)Cv)[(size_t)row * N2 + col] = v;
                    }
                }
        }
    }
}

extern "C" void kernel_launch(void* const* d_in, const int* in_sizes, int n_in,
                              void* d_out, int out_size, void* d_ws, size_t ws_size,
                              hipStream_t stream) {
    const float* x      = (const float*)d_in[0];
    const int*   ei     = (const int*)d_in[1];
    const float* W1g    = (const float*)d_in[2];   // (8,64,256): [0] = first 16384
    const float* root1  = (const float*)d_in[3];
    const float* b1     = (const float*)d_in[4];
    const float* W2g    = (const float*)d_in[5];   // (8,256,64): [0] = first 16384
    const float* root2  = (const float*)d_in[6];
    const float* b2     = (const float*)d_in[7];
    const float* dw1    = (const float*)d_in[8];
    const float* db1    = (const float*)d_in[9];
    const float* dw2    = (const float*)d_in[10];
    const float* db2    = (const float*)d_in[11];
    float* out = (float*)d_out;

    const int N = in_sizes[0] / 64;
    const int E = in_sizes[1] / 2;
    const int Npad = N + 64;
    const int* srcv = ei;
    const int* dstv = ei + E;

    char* ws = (char*)d_ws;
    auto alloc = [&](size_t bytes) -> void* {
        void* p = (void*)ws;
        ws += (bytes + 255) & ~(size_t)255;
        return p;
    };
    int*   bcnt   = (int*)alloc(1024);               // per-bucket counts (256)
    int*   deg    = (int*)alloc((size_t)N * 4);      // per-node degree (adjacent to bcnt)
    int*   offs   = (int*)alloc((size_t)(N + 1) * 4);
    int*   cur    = (int*)alloc((size_t)N * 4);      // scatter cursors
    float* invd   = (float*)alloc((size_t)N * 4);
    int*   esrc   = (int*)alloc((size_t)E * 4);
    unsigned short* Pb1 = (unsigned short*)alloc(32768 * 2);
    unsigned short* Pb2 = (unsigned short*)alloc(32768 * 2);
    unsigned short* Pd1 = (unsigned short*)alloc(16384 * 2);
    unsigned short* Pd2 = (unsigned short*)alloc(16384 * 2);
    unsigned short* ab1    = (unsigned short*)alloc((size_t)Npad * 128 * 2);  // [agg1 | xb]
    unsigned short* hwroot = (unsigned short*)alloc((size_t)Npad * 128 * 2);
    unsigned short* z      = (unsigned short*)alloc((size_t)Npad * 64 * 2);

    hipMemsetAsync(bcnt, 0, 1024 + (size_t)N * 4, stream);  // bcnt + deg (adjacent)

    int gb = (N + 63) / 64;
    int nbkt = (N + 255) / 256;
    int pa = (E + 4095) / 4096;
    int pb_pack = (98304 + N * 16 + THREADS - 1) / THREADS;

    // packs + x->bf16 + deg count + bucket histogram (one kernel, disjoint ranges)
    prep_kernel<<<pb_pack + pa, THREADS, 0, stream>>>(
        W1g, root1, W2g, root2, dw1, dw2, x, dstv, bcnt, deg,
        Pb1, Pb2, Pd1, Pd2, ab1, N, E, pb_pack);
    // CSR: offs/cur/invd from deg, then edge-parallel counting-sort scatter
    build_offs<<<nbkt, 256, 0, stream>>>(bcnt, deg, offs, cur, invd, N, E);
    scatter_edges<<<(E + 1023) / 1024, 256, 0, stream>>>(srcv, dstv, cur, esrc, E);

    // layer 1 agg + fused [L1 GEMM -> L2 projection]
    agg_x4<<<(N + 3) / 4, THREADS, 0, stream>>>(ab1, esrc, offs, invd, N);
    gemm_fused<128, 2, true><<<gb, 256, 0, stream>>>(ab1, Pb1, b1, Pb2, nullptr, hwroot, N);
    // layer 2 gather + epilogue
    agg_z4<<<(N + 3) / 4, THREADS, 0, stream>>>(hwroot, esrc, offs, invd, b2, z, N);
    // fused decoder [dec1 -> dec2]
    gemm_fused<64, 1, false><<<gb, 256, 0, stream>>>(z, Pd1, db1, Pd2, db2, out, N);
}